// Round 1
// baseline (492.041 us; speedup 1.0000x reference)
//
#include <hip/hip_runtime.h>
#include <math.h>

#define B 1024
#define N 2048
#define M 128
#define C 512
#define OD (M + 6)
#define EPSF 1e-8f

__device__ __forceinline__ float softplusf(float x) {
    return fmaxf(x, 0.f) + log1pf(expf(-fabsf(x)));
}
__device__ __forceinline__ float sigmoidf_(float x) {
    return 1.f / (1.f + expf(-x));
}

// Kernel 1: o = x @ W.T + b; split into k (first M), activations for the rest.
// One block per batch row.
__global__ __launch_bounds__(256) void k_head(
    const float* __restrict__ x, const float* __restrict__ W,
    const float* __restrict__ bias, float* __restrict__ kbuf,
    float* __restrict__ params)
{
    const int b = blockIdx.x;
    __shared__ float xs[C];
    __shared__ float os[OD];
    __shared__ float red[128];

    for (int i = threadIdx.x; i < C; i += 256) xs[i] = x[(size_t)b * C + i];
    __syncthreads();

    if (threadIdx.x < OD) {
        const int j = threadIdx.x;
        const float4* wr = (const float4*)(W + (size_t)j * C);
        float acc = 0.f;
#pragma unroll 8
        for (int c = 0; c < C / 4; ++c) {
            float4 wv = wr[c];
            acc = fmaf(wv.x, xs[4 * c + 0], acc);
            acc = fmaf(wv.y, xs[4 * c + 1], acc);
            acc = fmaf(wv.z, xs[4 * c + 2], acc);
            acc = fmaf(wv.w, xs[4 * c + 3], acc);
        }
        os[j] = acc + bias[j];
    }
    __syncthreads();

    if (threadIdx.x < M) {
        float v = os[threadIdx.x];
        kbuf[(size_t)b * M + threadIdx.x] = v;
        red[threadIdx.x] = v * v;
    }
    __syncthreads();
    for (int s = 64; s > 0; s >>= 1) {
        if (threadIdx.x < s) red[threadIdx.x] += red[threadIdx.x + s];
        __syncthreads();
    }
    if (threadIdx.x == 0) {
        float kn = sqrtf(red[0]);
        float beta = softplusf(os[M]);
        float g = sigmoidf_(os[M + 1]);
        float a0 = os[M + 2], a1 = os[M + 3], a2 = os[M + 4];
        float mx = fmaxf(a0, fmaxf(a1, a2));
        float e0 = expf(a0 - mx), e1 = expf(a1 - mx), e2 = expf(a2 - mx);
        float inv = 1.f / (e0 + e1 + e2);
        float gamma = 1.f + softplusf(os[M + 5]);
        float* p = params + (size_t)b * 8;
        p[0] = beta; p[1] = g; p[2] = e0 * inv; p[3] = e1 * inv;
        p[4] = e2 * inv; p[5] = gamma; p[6] = kn;
    }
}

// Kernel 2: pass 1 over mem. z[b,n] = beta * dot(mem[b,n,:],k[b]) /
// (||mem[b,n,:]|| * ||k[b]|| + eps). Half-wave (32 lanes) per row, float4/lane.
__global__ __launch_bounds__(256) void k_sim(
    const float* __restrict__ mem, const float* __restrict__ kbuf,
    const float* __restrict__ params, float* __restrict__ z)
{
    const int lane = threadIdx.x & 63;
    const int wid = threadIdx.x >> 6;
    const int half = lane >> 5;
    const int l32 = lane & 31;
    const long long totalRows = (long long)B * N;
    const long long totalWaves = (long long)gridDim.x * 4;
    const long long gw = (long long)blockIdx.x * 4 + wid;

    for (long long base = gw * 2; base < totalRows; base += totalWaves * 2) {
        const long long row = base + half;   // totalRows even, base even -> in range
        const int b = (int)(row >> 11);      // row / N
        const float4* mp = (const float4*)(mem + row * M);
        const float4* kp = (const float4*)(kbuf + (size_t)b * M);
        float4 mv = mp[l32];
        float4 kv = kp[l32];
        float dot = mv.x * kv.x + mv.y * kv.y + mv.z * kv.z + mv.w * kv.w;
        float sq  = mv.x * mv.x + mv.y * mv.y + mv.z * mv.z + mv.w * mv.w;
#pragma unroll
        for (int m = 16; m >= 1; m >>= 1) {
            dot += __shfl_xor(dot, m, 64);
            sq  += __shfl_xor(sq, m, 64);
        }
        if (l32 == 0) {
            float beta = params[(size_t)b * 8 + 0];
            float kn   = params[(size_t)b * 8 + 6];
            z[row] = beta * dot / (sqrtf(sq) * kn + EPSF);
        }
    }
}

// Kernel 3: per-row softmax over N, interpolation with w_prev, circular shift,
// sharpening, renormalize. One block (256 threads) per batch row.
__global__ __launch_bounds__(256) void k_weight(
    const float* __restrict__ z, const float* __restrict__ w_prev,
    const float* __restrict__ params, float* __restrict__ w_out)
{
    const int b = blockIdx.x;
    const int tid = threadIdx.x;
    __shared__ float buf[N];
    __shared__ float red[4];

    const float* zr = z + (long long)b * N;
    float zv[8];
    float lmax = -1e30f;
#pragma unroll
    for (int i = 0; i < 8; ++i) {
        zv[i] = zr[tid + i * 256];
        lmax = fmaxf(lmax, zv[i]);
    }
#pragma unroll
    for (int m = 32; m >= 1; m >>= 1) lmax = fmaxf(lmax, __shfl_xor(lmax, m, 64));
    if ((tid & 63) == 0) red[tid >> 6] = lmax;
    __syncthreads();
    const float gmax = fmaxf(fmaxf(red[0], red[1]), fmaxf(red[2], red[3]));

    float ev[8];
    float lsum = 0.f;
#pragma unroll
    for (int i = 0; i < 8; ++i) { ev[i] = expf(zv[i] - gmax); lsum += ev[i]; }
#pragma unroll
    for (int m = 32; m >= 1; m >>= 1) lsum += __shfl_xor(lsum, m, 64);
    __syncthreads();
    if ((tid & 63) == 0) red[tid >> 6] = lsum;
    __syncthreads();
    const float inv = 1.f / (red[0] + red[1] + red[2] + red[3]);

    const float g  = params[(size_t)b * 8 + 1];
    const float s0 = params[(size_t)b * 8 + 2];
    const float s1 = params[(size_t)b * 8 + 3];
    const float s2 = params[(size_t)b * 8 + 4];
    const float gamma = params[(size_t)b * 8 + 5];
    const float* wp = w_prev + (long long)b * N;
#pragma unroll
    for (int i = 0; i < 8; ++i) {
        int n = tid + i * 256;
        float wc = ev[i] * inv;
        buf[n] = g * wc + (1.f - g) * wp[n];
    }
    __syncthreads();

    float pw[8];
    float lps = 0.f;
#pragma unroll
    for (int i = 0; i < 8; ++i) {
        int n = tid + i * 256;
        int nm = (n == 0) ? (N - 1) : (n - 1);
        int np = (n == N - 1) ? 0 : (n + 1);
        float wt = s0 * buf[nm] + s1 * buf[n] + s2 * buf[np];
        pw[i] = powf(wt, gamma);
        lps += pw[i];
    }
#pragma unroll
    for (int m = 32; m >= 1; m >>= 1) lps += __shfl_xor(lps, m, 64);
    __syncthreads();
    if ((tid & 63) == 0) red[tid >> 6] = lps;
    __syncthreads();
    const float invt = 1.f / (red[0] + red[1] + red[2] + red[3] + 1e-16f);

    float* wo = w_out + (long long)b * N;
#pragma unroll
    for (int i = 0; i < 8; ++i) wo[tid + i * 256] = pw[i] * invt;
}

// Kernel 4: pass 2 over mem. r[b,:] = sum_n w[b,n] * mem[b,n,:].
// One block (8 waves) per batch row; wave handles n = wid, wid+8, ...;
// lane owns 2 consecutive m via float2; LDS cross-wave reduce.
__global__ __launch_bounds__(512) void k_read(
    const float* __restrict__ mem, const float* __restrict__ w,
    float* __restrict__ r)
{
    const int b = blockIdx.x;
    const int tid = threadIdx.x;
    const int lane = tid & 63;
    const int wid = tid >> 6;
    const float* mb = mem + (size_t)b * N * M;
    const float* wr = w + (size_t)b * N;
    const int m2 = lane * 2;

    float accx = 0.f, accy = 0.f;
    for (int n = wid; n < N; n += 8) {
        float2 mv = *(const float2*)(mb + (size_t)n * M + m2);
        float wv = wr[n];
        accx = fmaf(wv, mv.x, accx);
        accy = fmaf(wv, mv.y, accy);
    }
    __shared__ float red[8][128];
    *(float2*)&red[wid][m2] = make_float2(accx, accy);
    __syncthreads();
    if (tid < 128) {
        float s = 0.f;
#pragma unroll
        for (int ww = 0; ww < 8; ++ww) s += red[ww][tid];
        r[(size_t)b * M + tid] = s;
    }
}

extern "C" void kernel_launch(void* const* d_in, const int* in_sizes, int n_in,
                              void* d_out, int out_size, void* d_ws, size_t ws_size,
                              hipStream_t stream) {
    const float* x      = (const float*)d_in[0];
    const float* w_prev = (const float*)d_in[1];
    const float* mem    = (const float*)d_in[2];
    const float* W      = (const float*)d_in[3];
    const float* bias   = (const float*)d_in[4];

    float* r_out = (float*)d_out;                 // B*M
    float* w_out = (float*)d_out + (size_t)B * M; // B*N

    float* ws = (float*)d_ws;
    float* kbuf   = ws;                              // B*M
    float* params = ws + (size_t)B * M;              // B*8
    float* z      = ws + (size_t)B * M + (size_t)B * 8; // B*N

    k_head<<<B, 256, 0, stream>>>(x, W, bias, kbuf, params);
    k_sim<<<4096, 256, 0, stream>>>(mem, kbuf, params, z);
    k_weight<<<B, 256, 0, stream>>>(z, w_prev, params, w_out);
    k_read<<<B, 512, 0, stream>>>(mem, w_out, r_out);
}

// Round 2
// 388.728 us; speedup vs baseline: 1.2658x; 1.2658x over previous
//
#include <hip/hip_runtime.h>
#include <math.h>

#define B 1024
#define N 2048
#define M 128
#define C 512
#define OD (M + 6)
#define EPSF 1e-8f

__device__ __forceinline__ float softplusf(float x) {
    return fmaxf(x, 0.f) + log1pf(expf(-fabsf(x)));
}
__device__ __forceinline__ float sigmoidf_(float x) {
    return 1.f / (1.f + expf(-x));
}

// Kernel 1: o = x @ W.T + b; k (first M cols) + scalar head params.
// One block per batch row.
__global__ __launch_bounds__(256) void k_head(
    const float* __restrict__ x, const float* __restrict__ W,
    const float* __restrict__ bias, float* __restrict__ kbuf,
    float* __restrict__ params)
{
    const int b = blockIdx.x;
    __shared__ float xs[C];
    __shared__ float os[OD];
    __shared__ float red[128];

    for (int i = threadIdx.x; i < C; i += 256) xs[i] = x[(size_t)b * C + i];
    __syncthreads();

    if (threadIdx.x < OD) {
        const int j = threadIdx.x;
        const float4* wr = (const float4*)(W + (size_t)j * C);
        float acc = 0.f;
#pragma unroll 8
        for (int c = 0; c < C / 4; ++c) {
            float4 wv = wr[c];
            acc = fmaf(wv.x, xs[4 * c + 0], acc);
            acc = fmaf(wv.y, xs[4 * c + 1], acc);
            acc = fmaf(wv.z, xs[4 * c + 2], acc);
            acc = fmaf(wv.w, xs[4 * c + 3], acc);
        }
        os[j] = acc + bias[j];
    }
    __syncthreads();

    if (threadIdx.x < M) {
        float v = os[threadIdx.x];
        kbuf[(size_t)b * M + threadIdx.x] = v;
        red[threadIdx.x] = v * v;
    }
    __syncthreads();
    for (int s = 64; s > 0; s >>= 1) {
        if (threadIdx.x < s) red[threadIdx.x] += red[threadIdx.x + s];
        __syncthreads();
    }
    if (threadIdx.x == 0) {
        float kn = sqrtf(red[0]);
        float beta = softplusf(os[M]);
        float g = sigmoidf_(os[M + 1]);
        float a0 = os[M + 2], a1 = os[M + 3], a2 = os[M + 4];
        float mx = fmaxf(a0, fmaxf(a1, a2));
        float e0 = expf(a0 - mx), e1 = expf(a1 - mx), e2 = expf(a2 - mx);
        float inv = 1.f / (e0 + e1 + e2);
        float gamma = 1.f + softplusf(os[M + 5]);
        float* p = params + (size_t)b * 8;
        p[0] = beta; p[1] = g; p[2] = e0 * inv; p[3] = e1 * inv;
        p[4] = e2 * inv; p[5] = gamma; p[6] = kn;
    }
}

// Fused kernel: one block per batch row b. 1024 threads = 16 waves.
// Pass 1: z[n] = beta*cos_sim -> LDS. Block softmax + interpolate + shift +
// sharpen + renorm (all per-b). Pass 2 (REVERSE n order for L3 reuse):
// r = sum_n w[n]*mem[b,n,:].
// 96 KB static LDS forces 1 block/CU -> resident set = 256 blocks * 1 MB
// = 256 MB ~ L3, so reverse pass-2 re-reads hit Infinity Cache.
__global__ __launch_bounds__(1024) void k_fused(
    const float* __restrict__ mem, const float* __restrict__ kbuf,
    const float* __restrict__ params, const float* __restrict__ w_prev,
    float* __restrict__ w_out, float* __restrict__ r_out)
{
    __shared__ float smem[24576];   // 96 KB: occupancy limiter + z/buf storage
    float* zs  = smem;              // [N]  z -> later w
    float* buf = smem + N;          // [N]  wg -> later partial-r [16][128]
    __shared__ float red[16];

    const int b = blockIdx.x;
    const int tid = threadIdx.x;
    const int lane = tid & 63;
    const int wid  = tid >> 6;      // 0..15
    const int half = lane >> 5;
    const int l32  = lane & 31;
    const int hw   = wid * 2 + half; // 0..31: half-wave id
    const float* mb = mem + (size_t)b * N * M;

    const float4 kv = ((const float4*)(kbuf + (size_t)b * M))[l32];
    const float beta = params[(size_t)b * 8 + 0];
    const float kn   = params[(size_t)b * 8 + 6];

    // ---- pass 1: similarity z ----
    for (int n0 = 0; n0 < N; n0 += 128) {
        float4 mv[4];
#pragma unroll
        for (int j = 0; j < 4; ++j)
            mv[j] = ((const float4*)(mb + (size_t)(n0 + j * 32 + hw) * M))[l32];
#pragma unroll
        for (int j = 0; j < 4; ++j) {
            float dot = mv[j].x * kv.x + mv[j].y * kv.y + mv[j].z * kv.z + mv[j].w * kv.w;
            float sq  = mv[j].x * mv[j].x + mv[j].y * mv[j].y + mv[j].z * mv[j].z + mv[j].w * mv[j].w;
#pragma unroll
            for (int s = 16; s >= 1; s >>= 1) {
                dot += __shfl_xor(dot, s, 64);
                sq  += __shfl_xor(sq,  s, 64);
            }
            if (l32 == 0)
                zs[n0 + j * 32 + hw] = beta * dot / (sqrtf(sq) * kn + EPSF);
        }
    }
    __syncthreads();

    // ---- softmax over N + interpolate + shift + sharpen + renorm ----
    const float z0 = zs[tid], z1 = zs[tid + 1024];
    float lmax = fmaxf(z0, z1);
#pragma unroll
    for (int s = 32; s >= 1; s >>= 1) lmax = fmaxf(lmax, __shfl_xor(lmax, s, 64));
    if (lane == 0) red[wid] = lmax;
    __syncthreads();
    float gmax = red[0];
#pragma unroll
    for (int i = 1; i < 16; ++i) gmax = fmaxf(gmax, red[i]);

    const float e0 = expf(z0 - gmax), e1 = expf(z1 - gmax);
    float lsum = e0 + e1;
#pragma unroll
    for (int s = 32; s >= 1; s >>= 1) lsum += __shfl_xor(lsum, s, 64);
    __syncthreads();
    if (lane == 0) red[wid] = lsum;
    __syncthreads();
    float ssum = 0.f;
#pragma unroll
    for (int i = 0; i < 16; ++i) ssum += red[i];
    const float inv = 1.f / ssum;

    const float g     = params[(size_t)b * 8 + 1];
    const float s0p   = params[(size_t)b * 8 + 2];
    const float s1p   = params[(size_t)b * 8 + 3];
    const float s2p   = params[(size_t)b * 8 + 4];
    const float gamma = params[(size_t)b * 8 + 5];
    const float* wp = w_prev + (size_t)b * N;
    buf[tid]        = g * (e0 * inv) + (1.f - g) * wp[tid];
    buf[tid + 1024] = g * (e1 * inv) + (1.f - g) * wp[tid + 1024];
    __syncthreads();

    float pw0, pw1;
    {
        const int n = tid;
        const int nm = n ? n - 1 : N - 1;
        const float wt = s0p * buf[nm] + s1p * buf[n] + s2p * buf[n + 1];
        pw0 = powf(wt, gamma);
    }
    {
        const int n = tid + 1024;
        const int np = (n == N - 1) ? 0 : n + 1;
        const float wt = s0p * buf[n - 1] + s1p * buf[n] + s2p * buf[np];
        pw1 = powf(wt, gamma);
    }
    float lps = pw0 + pw1;
#pragma unroll
    for (int s = 32; s >= 1; s >>= 1) lps += __shfl_xor(lps, s, 64);
    __syncthreads();
    if (lane == 0) red[wid] = lps;
    __syncthreads();
    float tsum = 0.f;
#pragma unroll
    for (int i = 0; i < 16; ++i) tsum += red[i];
    const float invt = 1.f / (tsum + 1e-16f);

    const float w0 = pw0 * invt, w1 = pw1 * invt;
    zs[tid] = w0; zs[tid + 1024] = w1;
    float* wo = w_out + (size_t)b * N;
    wo[tid] = w0; wo[tid + 1024] = w1;
    __syncthreads();

    // ---- pass 2: r = sum_n w[n]*mem[b,n,:], reverse order for cache reuse ----
    float4 acc = make_float4(0.f, 0.f, 0.f, 0.f);
    for (int n0 = N - 128; n0 >= 0; n0 -= 128) {
        float4 mv[4];
        float wv[4];
#pragma unroll
        for (int j = 0; j < 4; ++j) {
            const int n = n0 + j * 32 + hw;
            mv[j] = ((const float4*)(mb + (size_t)n * M))[l32];
            wv[j] = zs[n];
        }
#pragma unroll
        for (int j = 0; j < 4; ++j) {
            acc.x = fmaf(wv[j], mv[j].x, acc.x);
            acc.y = fmaf(wv[j], mv[j].y, acc.y);
            acc.z = fmaf(wv[j], mv[j].z, acc.z);
            acc.w = fmaf(wv[j], mv[j].w, acc.w);
        }
    }
    // combine the two halves of each wave (same m-slice, different rows)
    acc.x += __shfl_xor(acc.x, 32, 64);
    acc.y += __shfl_xor(acc.y, 32, 64);
    acc.z += __shfl_xor(acc.z, 32, 64);
    acc.w += __shfl_xor(acc.w, 32, 64);
    if (half == 0)
        *(float4*)&buf[wid * 128 + l32 * 4] = acc;
    __syncthreads();
    if (tid < M) {
        float s = 0.f;
#pragma unroll
        for (int w = 0; w < 16; ++w) s += buf[w * 128 + tid];
        r_out[(size_t)b * M + tid] = s;
    }
}

extern "C" void kernel_launch(void* const* d_in, const int* in_sizes, int n_in,
                              void* d_out, int out_size, void* d_ws, size_t ws_size,
                              hipStream_t stream) {
    const float* x      = (const float*)d_in[0];
    const float* w_prev = (const float*)d_in[1];
    const float* mem    = (const float*)d_in[2];
    const float* W      = (const float*)d_in[3];
    const float* bias   = (const float*)d_in[4];

    float* r_out = (float*)d_out;                 // B*M
    float* w_out = (float*)d_out + (size_t)B * M; // B*N

    float* ws = (float*)d_ws;
    float* kbuf   = ws;                 // B*M
    float* params = ws + (size_t)B * M; // B*8

    k_head<<<B, 256, 0, stream>>>(x, W, bias, kbuf, params);
    k_fused<<<B, 1024, 0, stream>>>(mem, kbuf, params, w_prev, w_out, r_out);
}